// Round 4
// baseline (404.053 us; speedup 1.0000x reference)
//
#include <hip/hip_runtime.h>
#include <hip/hip_bf16.h>

// ---------------------------------------------------------------------------
// Trojan_GCN round 4:
//  - CSR gather aggregation, layer-2 commuted + trigger-restricted (round 3)
//  - GEMM: reg-staged double buffer (prefetch K-step t+1 during compute of t),
//    KT=32, split-quad micro fragments (2-way LDS conflicts only)
//  - gather: wave-per-row, float4 lanes, 2 edges per wave-load
// ---------------------------------------------------------------------------

__global__ __launch_bounds__(256) void deg_kernel(
    const int* __restrict__ src, const int* __restrict__ dst,
    int* __restrict__ deg_out, int* __restrict__ deg_in, int E)
{
    int i = blockIdx.x * blockDim.x + threadIdx.x;
    if (i < E) {
        atomicAdd(&deg_out[src[i]], 1);
        atomicAdd(&deg_in[dst[i]], 1);
    }
}

__global__ __launch_bounds__(256) void norm_kernel(
    const int* __restrict__ deg_out, const int* __restrict__ deg_in,
    float* __restrict__ norm_out, float* __restrict__ norm_in, int N)
{
    int i = blockIdx.x * blockDim.x + threadIdx.x;
    if (i < N) {
        norm_out[i] = rsqrtf(fmaxf((float)deg_out[i], 1.0f));
        norm_in[i]  = rsqrtf(fmaxf((float)deg_in[i], 1.0f));
    }
}

// --- 3-kernel exclusive scan of deg_in into rowptr[1..N] (rowptr[0]=0) ---
__global__ __launch_bounds__(256) void scan1_kernel(
    const int* __restrict__ deg, int* __restrict__ rowptr,
    int* __restrict__ bsum, int N)
{
    __shared__ int s[256];
    int t = threadIdx.x;
    int i = blockIdx.x * 256 + t;
    s[t] = (i < N) ? deg[i] : 0;
    __syncthreads();
    #pragma unroll
    for (int off = 1; off < 256; off <<= 1) {
        int v = (t >= off) ? s[t - off] : 0;
        __syncthreads();
        s[t] += v;
        __syncthreads();
    }
    if (i < N) rowptr[i + 1] = s[t];
    if (t == 255) bsum[blockIdx.x] = s[255];
}

__global__ __launch_bounds__(256) void scan2_kernel(int* __restrict__ bsum, int nb)
{
    __shared__ int s[256];
    int t = threadIdx.x;
    s[t] = (t < nb) ? bsum[t] : 0;
    __syncthreads();
    #pragma unroll
    for (int off = 1; off < 256; off <<= 1) {
        int v = (t >= off) ? s[t - off] : 0;
        __syncthreads();
        s[t] += v;
        __syncthreads();
    }
    if (t < nb) bsum[t] = s[t];
}

__global__ __launch_bounds__(256) void scan3_kernel(
    int* __restrict__ rowptr, const int* __restrict__ bsum, int N)
{
    int b = blockIdx.x;
    int i = b * 256 + threadIdx.x;
    if (i < N) {
        int add = (b > 0) ? bsum[b - 1] : 0;
        rowptr[i + 1] += add;
    }
    if (i == 0) rowptr[0] = 0;
}

// ecol[rowptr[dst[e]] + slot] = src[e]
__global__ __launch_bounds__(256) void fill_kernel(
    const int* __restrict__ src, const int* __restrict__ dst,
    const int* __restrict__ rowptr, int* __restrict__ cursor,
    int* __restrict__ ecol, int E)
{
    int e = blockIdx.x * blockDim.x + threadIdx.x;
    if (e < E) {
        int r = dst[e];
        int slot = atomicAdd(&cursor[r], 1);
        ecol[rowptr[r] + slot] = src[e];
    }
}

// out[r, :] = sum_{in-edges e of r} x[src_e, :] * nsrc[src_e]   (D=128)
// wave-per-row; lane = (edge parity h, col quad q); 2 edges per wave-load.
__global__ __launch_bounds__(256) void gather4_kernel(
    const float* __restrict__ x, const float* __restrict__ nsrc,
    const int* __restrict__ rowptr, const int* __restrict__ ecol,
    float* __restrict__ out, int N)
{
    const int wave = threadIdx.x >> 6;
    const int lane = threadIdx.x & 63;
    const int r = blockIdx.x * 4 + wave;
    if (r >= N) return;
    const int q = lane & 31;   // col quad
    const int h = lane >> 5;   // edge parity
    const int beg = rowptr[r], end = rowptr[r + 1];
    const float4* __restrict__ x4 = (const float4*)x;

    float4 acc = make_float4(0.f, 0.f, 0.f, 0.f);
    int k = beg + h;
    int s = (k < end) ? ecol[k] : 0;
    for (; k < end; k += 2) {
        int sn = (k + 2 < end) ? ecol[k + 2] : 0;
        float ns = nsrc[s];
        float4 v = x4[(long)s * 32 + q];
        acc.x += v.x * ns; acc.y += v.y * ns;
        acc.z += v.z * ns; acc.w += v.w * ns;
        s = sn;
    }
    acc.x += __shfl(acc.x, lane ^ 32);
    acc.y += __shfl(acc.y, lane ^ 32);
    acc.z += __shfl(acc.z, lane ^ 32);
    acc.w += __shfl(acc.w, lane ^ 32);
    if (h == 0) ((float4*)out)[(long)r * 32 + q] = acc;
}

// h2t[b, :] = relu( norm_in[r] * sum_{in-edges e of r} z[src_e, :] + b2 ),
// r = trig[b]
__global__ __launch_bounds__(256) void gather_trig4_kernel(
    const float* __restrict__ z, const int* __restrict__ trig,
    const float* __restrict__ norm_in, const float* __restrict__ b2,
    const int* __restrict__ rowptr, const int* __restrict__ ecol,
    float* __restrict__ h2t, int T)
{
    const int wave = threadIdx.x >> 6;
    const int lane = threadIdx.x & 63;
    const int b = blockIdx.x * 4 + wave;
    if (b >= T) return;
    const int q = lane & 31;
    const int h = lane >> 5;
    const int r = trig[b];
    const int beg = rowptr[r], end = rowptr[r + 1];
    const float4* __restrict__ z4 = (const float4*)z;

    float4 acc = make_float4(0.f, 0.f, 0.f, 0.f);
    int k = beg + h;
    int s = (k < end) ? ecol[k] : 0;
    for (; k < end; k += 2) {
        int sn = (k + 2 < end) ? ecol[k + 2] : 0;
        float4 v = z4[(long)s * 32 + q];
        acc.x += v.x; acc.y += v.y; acc.z += v.z; acc.w += v.w;
        s = sn;
    }
    acc.x += __shfl(acc.x, lane ^ 32);
    acc.y += __shfl(acc.y, lane ^ 32);
    acc.z += __shfl(acc.z, lane ^ 32);
    acc.w += __shfl(acc.w, lane ^ 32);
    if (h == 0) {
        const float ni = norm_in[r];
        const float4 bb = ((const float4*)b2)[q];
        float4 o;
        o.x = fmaxf(fmaf(ni, acc.x, bb.x), 0.f);
        o.y = fmaxf(fmaf(ni, acc.y, bb.y), 0.f);
        o.z = fmaxf(fmaf(ni, acc.z, bb.z), 0.f);
        o.w = fmaxf(fmaf(ni, acc.w, bb.w), 0.f);
        ((float4*)h2t)[(long)b * 32 + q] = o;
    }
}

// C[r,c] = act( rowscale[r]*sum_k A[r,k]*B[k,c] + bias[c] ) * outscale[r]
// 256 threads (16x16), micro MR x NR with quad-split fragments, KT=32,
// reg-staged double buffer. TM=16*MR, TN=16*NR. N%TN==0, K%32==0.
template<int MR, int NR, bool RELU>
__global__ __launch_bounds__(256) void gemm_kernel(
    const float* __restrict__ A, const float* __restrict__ B,
    const float* __restrict__ bias, const float* __restrict__ rowscale,
    const float* __restrict__ outscale,
    float* __restrict__ C, int M, int N, int K)
{
    constexpr int TM = 16 * MR, TN = 16 * NR, KT = 32;
    constexpr int AL = TM * KT / 4 / 256;
    constexpr int BL = TN * KT / 4 / 256;
    __shared__ float As[KT][TM + 4];
    __shared__ float Bs[KT][TN];

    const int tid = threadIdx.x;
    const int tx = tid & 15, ty = tid >> 4;
    const int row0 = blockIdx.y * TM;
    const int col0 = blockIdx.x * TN;

    int am[AL], aq[AL]; long aoff[AL]; float asc[AL]; bool av[AL];
    #pragma unroll
    for (int l = 0; l < AL; ++l) {
        int idx = tid + l * 256;
        am[l] = idx >> 3; aq[l] = idx & 7;          // KT/4 = 8 quads
        int r = row0 + am[l];
        av[l] = (r < M);
        aoff[l] = (long)(av[l] ? r : 0) * K + aq[l] * 4;
        asc[l] = (av[l] && rowscale) ? rowscale[r] : 1.0f;
    }
    int bk[BL], bq[BL];
    #pragma unroll
    for (int l = 0; l < BL; ++l) {
        int idx = tid + l * 256;
        bk[l] = idx / (TN / 4); bq[l] = idx % (TN / 4);
    }

    float4 pa[AL], pb[BL];
    auto loadAB = [&](int kb) {
        #pragma unroll
        for (int l = 0; l < AL; ++l)
            pa[l] = av[l] ? *reinterpret_cast<const float4*>(&A[aoff[l] + kb])
                          : make_float4(0.f, 0.f, 0.f, 0.f);
        #pragma unroll
        for (int l = 0; l < BL; ++l)
            pb[l] = *reinterpret_cast<const float4*>(
                &B[(long)(kb + bk[l]) * N + col0 + bq[l] * 4]);
    };

    float acc[MR][NR] = {};

    loadAB(0);
    for (int kb = 0;;) {
        #pragma unroll
        for (int l = 0; l < AL; ++l) {
            As[aq[l] * 4 + 0][am[l]] = pa[l].x * asc[l];
            As[aq[l] * 4 + 1][am[l]] = pa[l].y * asc[l];
            As[aq[l] * 4 + 2][am[l]] = pa[l].z * asc[l];
            As[aq[l] * 4 + 3][am[l]] = pa[l].w * asc[l];
        }
        #pragma unroll
        for (int l = 0; l < BL; ++l)
            *reinterpret_cast<float4*>(&Bs[bk[l]][bq[l] * 4]) = pb[l];
        __syncthreads();

        const bool last = (kb + KT >= K);
        if (!last) loadAB(kb + KT);   // in flight during compute

        #pragma unroll 8
        for (int kk = 0; kk < KT; ++kk) {
            float a[MR], b[NR];
            {
                float4 t = *reinterpret_cast<const float4*>(&As[kk][ty * 4]);
                a[0] = t.x; a[1] = t.y; a[2] = t.z; a[3] = t.w;
            }
            if constexpr (MR == 8) {
                float4 t = *reinterpret_cast<const float4*>(&As[kk][TM / 2 + ty * 4]);
                a[4] = t.x; a[5] = t.y; a[6] = t.z; a[7] = t.w;
            }
            {
                float4 t = *reinterpret_cast<const float4*>(&Bs[kk][tx * 4]);
                b[0] = t.x; b[1] = t.y; b[2] = t.z; b[3] = t.w;
            }
            if constexpr (NR == 8) {
                float4 t = *reinterpret_cast<const float4*>(&Bs[kk][TN / 2 + tx * 4]);
                b[4] = t.x; b[5] = t.y; b[6] = t.z; b[7] = t.w;
            }
            #pragma unroll
            for (int i = 0; i < MR; ++i)
                #pragma unroll
                for (int j = 0; j < NR; ++j)
                    acc[i][j] = fmaf(a[i], b[j], acc[i][j]);
        }
        if (last) break;
        __syncthreads();
        kb += KT;
    }

    #pragma unroll
    for (int i = 0; i < MR; ++i) {
        const int ri = (MR == 8) ? ((i < 4) ? ty * 4 + i : TM / 2 + ty * 4 + (i - 4))
                                 : ty * 4 + i;
        const int r = row0 + ri;
        if (r >= M) continue;
        const float osc = outscale ? outscale[r] : 1.0f;
        #pragma unroll
        for (int j = 0; j < NR; ++j) {
            const int cj = (NR == 8) ? ((j < 4) ? tx * 4 + j : TN / 2 + tx * 4 + (j - 4))
                                     : tx * 4 + j;
            const int c = col0 + cj;
            float v = acc[i][j] + (bias ? bias[c] : 0.0f);
            if (RELU) v = fmaxf(v, 0.0f);
            C[(long)r * N + c] = v * osc;
        }
    }
}

static inline long align4(long x) { return (x + 3) & ~3L; }

extern "C" void kernel_launch(void* const* d_in, const int* in_sizes, int n_in,
                              void* d_out, int out_size, void* d_ws, size_t ws_size,
                              hipStream_t stream)
{
    const float* features = (const float*)d_in[0];
    const int*   src      = (const int*)d_in[1];
    const int*   dst      = (const int*)d_in[2];
    const int*   trig     = (const int*)d_in[3];
    const float* W1  = (const float*)d_in[4];
    const float* b1  = (const float*)d_in[5];
    const float* W2  = (const float*)d_in[6];
    const float* b2  = (const float*)d_in[7];
    const float* Wf  = (const float*)d_in[8];
    const float* bf  = (const float*)d_in[9];
    const float* Wf1 = (const float*)d_in[10];
    const float* bf1 = (const float*)d_in[11];
    const float* We  = (const float*)d_in[12];
    const float* be  = (const float*)d_in[13];
    const float* We1 = (const float*)d_in[14];
    const float* be1 = (const float*)d_in[15];

    const int  d   = 128, h2d = 256, od = 64;
    const int  N   = in_sizes[0] / d;      // 50000
    const int  E   = in_sizes[1];          // 800000
    const int  T   = in_sizes[3];          // 4096
    const int  NB  = (N + 255) / 256;      // 196 <= 256

    // ---- workspace layout ----
    char* wsb = (char*)d_ws;
    long off = 0;
    auto takeF = [&](long n) { float* p = (float*)(wsb + off * 4); off += align4(n); return p; };
    auto takeI = [&](long n) { int*   p = (int*)  (wsb + off * 4); off += align4(n); return p; };

    float* norm_out = takeF(N);
    float* norm_in  = takeF(N);
    int*   rowptr   = takeI(N + 1);
    int*   degout   = takeI(N);        // degout/degin/cursor contiguous: one memset
    int*   degin    = takeI(N);
    int*   cursor   = takeI(N);
    int*   bsum     = takeI(256);
    int*   ecol     = takeI(E);
    float* agg1     = takeF((long)N * d);    // [N,128]
    float* z        = takeF((long)N * d);    // [N,128]
    float* h1s      = takeF((long)N * h2d);  // [N,256]
    float* h2t      = takeF((long)T * d);    // [T,128]
    float* tmpf     = takeF((long)T * d);    // [T,128]
    float* tmpe     = takeF((long)T * od);   // [T,64]

    float* out_feat = (float*)d_out;              // [T,128]
    float* out_edge = out_feat + (long)T * d;     // [T,64]

    // ---- CSR build + norms ----
    hipMemsetAsync(degout, 0, (size_t)(3 * align4(N)) * sizeof(int), stream);

    deg_kernel<<<dim3((E + 255) / 256), dim3(256), 0, stream>>>(
        src, dst, degout, degin, E);
    norm_kernel<<<dim3((N + 255) / 256), dim3(256), 0, stream>>>(
        degout, degin, norm_out, norm_in, N);
    scan1_kernel<<<dim3(NB), dim3(256), 0, stream>>>(degin, rowptr, bsum, N);
    scan2_kernel<<<dim3(1), dim3(256), 0, stream>>>(bsum, NB);
    scan3_kernel<<<dim3(NB), dim3(256), 0, stream>>>(rowptr, bsum, N);
    fill_kernel<<<dim3((E + 255) / 256), dim3(256), 0, stream>>>(
        src, dst, rowptr, cursor, ecol, E);

    // ---- layer 1: agg1 = A @ (features*no); h1s = relu(ni*agg1@W1+b1)*no ----
    gather4_kernel<<<dim3((N + 3) / 4), dim3(256), 0, stream>>>(
        features, norm_out, rowptr, ecol, agg1, N);
    gemm_kernel<8, 8, true>
        <<<dim3(h2d / 128, (N + 127) / 128), dim3(256), 0, stream>>>(
        agg1, W1, b1, norm_in, norm_out, h1s, N, h2d, d);

    // ---- layer 2 (commuted): z = h1s @ W2; h2t = relu(ni*(A@z)[trig]+b2) ----
    gemm_kernel<8, 4, false>
        <<<dim3(d / 64, (N + 127) / 128), dim3(256), 0, stream>>>(
        h1s, W2, nullptr, nullptr, nullptr, z, N, d, h2d);
    gather_trig4_kernel<<<dim3((T + 3) / 4), dim3(256), 0, stream>>>(
        z, trig, norm_in, b2, rowptr, ecol, h2t, T);

    // ---- feat head ----
    gemm_kernel<4, 4, true>
        <<<dim3(d / 64, (T + 63) / 64), dim3(256), 0, stream>>>(
        h2t, Wf, bf, nullptr, nullptr, tmpf, T, d, d);
    gemm_kernel<4, 4, false>
        <<<dim3(d / 64, (T + 63) / 64), dim3(256), 0, stream>>>(
        tmpf, Wf1, bf1, nullptr, nullptr, out_feat, T, d, d);

    // ---- edge head ----
    gemm_kernel<4, 4, true>
        <<<dim3(od / 64, (T + 63) / 64), dim3(256), 0, stream>>>(
        h2t, We, be, nullptr, nullptr, tmpe, T, od, d);
    gemm_kernel<4, 4, false>
        <<<dim3(od / 64, (T + 63) / 64), dim3(256), 0, stream>>>(
        tmpe, We1, be1, nullptr, nullptr, out_edge, T, od, od);
}